// Round 2
// baseline (201.089 us; speedup 1.0000x reference)
//
#include <hip/hip_runtime.h>

// Problem constants (from reference)
#define NNZ_TOT     2097152
#define N_CELLS     4096
#define NUM_HID     128

// One 64-lane wave per output row. Rows in x_rows are sorted, so each wave
// binary-searches its nnz range [lo, hi). Lane owns hidden dims
// [lane*2, lane*2+2) as a float2 -> a row read is a coalesced 512B gather.
// The loop index is wave-uniform, so xv/xc/gidx reads are scalar loads;
// manual unroll x8 keeps 8 independent gather chains in flight.
// Every row is written by exactly one wave -> no atomics, no memset.

__device__ __forceinline__ int lower_bound(const int* __restrict__ a,
                                           int lo, int hi, int key) {
    while (lo < hi) {
        int mid = (lo + hi) >> 1;
        if (a[mid] < key) lo = mid + 1; else hi = mid;
    }
    return lo;
}

__global__ __launch_bounds__(256) void omics_rowwave_kernel(
    const float* __restrict__ xv,   // [NNZ] values
    const int*   __restrict__ xr,   // [NNZ] rows (sorted)
    const int*   __restrict__ xc,   // [NNZ] cols
    const int*   __restrict__ gidx, // [N_INPUT_GENES] gene -> embedding row
    const float* __restrict__ embs, // [N_PRETRAINED, 128]
    float*       __restrict__ out)  // [N_CELLS, 128]
{
    const int wave = (blockIdx.x * blockDim.x + threadIdx.x) >> 6;
    const int lane = threadIdx.x & 63;
    if (wave >= N_CELLS) return;

    const int r = wave;
    const int lo = lower_bound(xr, 0,  NNZ_TOT, r);
    const int hi = lower_bound(xr, lo, NNZ_TOT, r + 1);
    const int h  = lane * 2;

    float2 acc = make_float2(0.f, 0.f);

    int i = lo;
    const int n8 = lo + ((hi - lo) & ~7);
    for (; i < n8; i += 8) {
        // 8 independent (uniform) triple chains
        float v0 = xv[i+0], v1 = xv[i+1], v2 = xv[i+2], v3 = xv[i+3];
        float v4 = xv[i+4], v5 = xv[i+5], v6 = xv[i+6], v7 = xv[i+7];
        int c0 = xc[i+0], c1 = xc[i+1], c2 = xc[i+2], c3 = xc[i+3];
        int c4 = xc[i+4], c5 = xc[i+5], c6 = xc[i+6], c7 = xc[i+7];
        int g0 = gidx[c0], g1 = gidx[c1], g2 = gidx[c2], g3 = gidx[c3];
        int g4 = gidx[c4], g5 = gidx[c5], g6 = gidx[c6], g7 = gidx[c7];

        const float2 f0 = *reinterpret_cast<const float2*>(&embs[(long)g0 * NUM_HID + h]);
        const float2 f1 = *reinterpret_cast<const float2*>(&embs[(long)g1 * NUM_HID + h]);
        const float2 f2 = *reinterpret_cast<const float2*>(&embs[(long)g2 * NUM_HID + h]);
        const float2 f3 = *reinterpret_cast<const float2*>(&embs[(long)g3 * NUM_HID + h]);
        const float2 f4 = *reinterpret_cast<const float2*>(&embs[(long)g4 * NUM_HID + h]);
        const float2 f5 = *reinterpret_cast<const float2*>(&embs[(long)g5 * NUM_HID + h]);
        const float2 f6 = *reinterpret_cast<const float2*>(&embs[(long)g6 * NUM_HID + h]);
        const float2 f7 = *reinterpret_cast<const float2*>(&embs[(long)g7 * NUM_HID + h]);

        acc.x = fmaf(v0, f0.x, acc.x); acc.y = fmaf(v0, f0.y, acc.y);
        acc.x = fmaf(v1, f1.x, acc.x); acc.y = fmaf(v1, f1.y, acc.y);
        acc.x = fmaf(v2, f2.x, acc.x); acc.y = fmaf(v2, f2.y, acc.y);
        acc.x = fmaf(v3, f3.x, acc.x); acc.y = fmaf(v3, f3.y, acc.y);
        acc.x = fmaf(v4, f4.x, acc.x); acc.y = fmaf(v4, f4.y, acc.y);
        acc.x = fmaf(v5, f5.x, acc.x); acc.y = fmaf(v5, f5.y, acc.y);
        acc.x = fmaf(v6, f6.x, acc.x); acc.y = fmaf(v6, f6.y, acc.y);
        acc.x = fmaf(v7, f7.x, acc.x); acc.y = fmaf(v7, f7.y, acc.y);
    }
    for (; i < hi; ++i) {
        const float v = xv[i];
        const int   g = gidx[xc[i]];
        const float2 f = *reinterpret_cast<const float2*>(&embs[(long)g * NUM_HID + h]);
        acc.x = fmaf(v, f.x, acc.x);
        acc.y = fmaf(v, f.y, acc.y);
    }

    *reinterpret_cast<float2*>(&out[(long)r * NUM_HID + h]) = acc;
}

extern "C" void kernel_launch(void* const* d_in, const int* in_sizes, int n_in,
                              void* d_out, int out_size, void* d_ws, size_t ws_size,
                              hipStream_t stream) {
    const float* xv   = (const float*)d_in[0];
    const int*   xr   = (const int*)  d_in[1];
    const int*   xc   = (const int*)  d_in[2];
    const int*   gidx = (const int*)  d_in[3];
    const float* embs = (const float*)d_in[4];
    float*       out  = (float*)d_out;

    // One wave per row: 4096 waves -> 1024 blocks x 256 threads.
    // Every output element is written exactly once -> no memset needed.
    const int n_waves = N_CELLS;
    const int blocks  = (n_waves * 64) / 256;
    omics_rowwave_kernel<<<blocks, 256, 0, stream>>>(xv, xr, xc, gidx, embs, out);
}

// Round 3
// 174.373 us; speedup vs baseline: 1.1532x; 1.1532x over previous
//
#include <hip/hip_runtime.h>

// Problem constants (from reference)
#define NNZ_TOT   2097152
#define N_CELLS   4096
#define NUM_HID   128
#define CHUNK     128                   // nnz per wave
#define N_WAVES   (NNZ_TOT / CHUNK)     // 16384 waves -> 64/CU demand

// ---------------------------------------------------------------------------
// Kernel 1: fuse the first indirection: g_arr[i] = gidx[xc[i]].
// Coalesced read/write; gidx table is 80 KB (L1/L2 resident). ~5 us.
// ---------------------------------------------------------------------------
__global__ __launch_bounds__(256) void fuse_gidx_kernel(
    const int* __restrict__ xc, const int* __restrict__ gidx,
    int* __restrict__ g_arr)
{
    const int i = blockIdx.x * blockDim.x + threadIdx.x;
    if (i < NNZ_TOT) g_arr[i] = gidx[xc[i]];
}

// ---------------------------------------------------------------------------
// Kernel 2: one wave per 128-nnz contiguous chunk. Lane owns hidden dims
// [lane*2, lane*2+2) as float2 -> each embs-row read is a coalesced 512 B
// gather. Control data (rows/values/gene ids) is read through SGPRs
// (readfirstlane-forced s_load) so branches are wave-uniform and the vector
// memory pipe carries only the 8-deep independent embs gathers.
// Rows are sorted -> register accumulate, atomic flush on row change.
// ---------------------------------------------------------------------------
__device__ __forceinline__ void flush_row(float* __restrict__ out, int row,
                                          int h, float2 acc) {
    float* o = &out[(long)row * NUM_HID + h];
    atomicAdd(o + 0, acc.x);
    atomicAdd(o + 1, acc.y);
}

template <bool PRE>
__global__ __launch_bounds__(256) void omics_chunk_kernel(
    const float* __restrict__ xv,    // [NNZ] values
    const int*   __restrict__ xr,    // [NNZ] rows (sorted)
    const int*   __restrict__ xc,    // [NNZ] cols
    const int*   __restrict__ gidx,  // [N_INPUT_GENES]
    const int*   __restrict__ g_arr, // [NNZ] fused gene ids (if PRE)
    const float* __restrict__ embs,  // [N_PRETRAINED, 128]
    float*       __restrict__ out)   // [N_CELLS, 128]
{
    const int wave = (blockIdx.x * blockDim.x + threadIdx.x) >> 6;
    const int lane = threadIdx.x & 63;
    const int base = wave * CHUNK;
    const int h    = lane * 2;

    float2 acc = make_float2(0.f, 0.f);
    int cur = -1;

    for (int it = 0; it < CHUNK; it += 8) {
        const int i0 = __builtin_amdgcn_readfirstlane(base + it);
        const int rA = xr[i0];
        const int rB = xr[i0 + 7];

        if (rA == rB) {
            // Whole 8-group in one row (common case; rows avg ~512 nnz)
            if (rA != cur) {
                if (cur >= 0) flush_row(out, cur, h, acc);
                cur = rA;
                acc = make_float2(0.f, 0.f);
            }
            int   g[8];
            float v[8];
            #pragma unroll
            for (int j = 0; j < 8; ++j) {
                g[j] = PRE ? g_arr[i0 + j] : gidx[xc[i0 + j]];
                v[j] = xv[i0 + j];
            }
            float2 f[8];
            #pragma unroll
            for (int j = 0; j < 8; ++j)
                f[j] = *reinterpret_cast<const float2*>(
                    &embs[(long)g[j] * NUM_HID + h]);
            #pragma unroll
            for (int j = 0; j < 8; ++j) {
                acc.x = fmaf(v[j], f[j].x, acc.x);
                acc.y = fmaf(v[j], f[j].y, acc.y);
            }
        } else {
            // Row boundary inside the 8-group (rare): element-wise, still
            // wave-uniform control.
            #pragma unroll
            for (int j = 0; j < 8; ++j) {
                const int r = xr[i0 + j];
                if (r != cur) {
                    if (cur >= 0) flush_row(out, cur, h, acc);
                    cur = r;
                    acc = make_float2(0.f, 0.f);
                }
                const int   gg = PRE ? g_arr[i0 + j] : gidx[xc[i0 + j]];
                const float vv = xv[i0 + j];
                const float2 ff = *reinterpret_cast<const float2*>(
                    &embs[(long)gg * NUM_HID + h]);
                acc.x = fmaf(vv, ff.x, acc.x);
                acc.y = fmaf(vv, ff.y, acc.y);
            }
        }
    }
    if (cur >= 0) flush_row(out, cur, h, acc);
}

extern "C" void kernel_launch(void* const* d_in, const int* in_sizes, int n_in,
                              void* d_out, int out_size, void* d_ws, size_t ws_size,
                              hipStream_t stream) {
    const float* xv   = (const float*)d_in[0];
    const int*   xr   = (const int*)  d_in[1];
    const int*   xc   = (const int*)  d_in[2];
    const int*   gidx = (const int*)  d_in[3];
    const float* embs = (const float*)d_in[4];
    float*       out  = (float*)d_out;

    // Atomically accumulated -> zero first (harness poisons with 0xAA).
    hipMemsetAsync(out, 0, (size_t)out_size * sizeof(float), stream);

    const int blocks = (N_WAVES * 64) / 256;   // 4096 blocks x 256 threads

    if (ws_size >= (size_t)NNZ_TOT * sizeof(int)) {
        int* g_arr = (int*)d_ws;
        fuse_gidx_kernel<<<(NNZ_TOT + 255) / 256, 256, 0, stream>>>(xc, gidx, g_arr);
        omics_chunk_kernel<true><<<blocks, 256, 0, stream>>>(
            xv, xr, xc, gidx, g_arr, embs, out);
    } else {
        omics_chunk_kernel<false><<<blocks, 256, 0, stream>>>(
            xv, xr, xc, gidx, (const int*)nullptr, embs, out);
    }
}